// Round 11
// baseline (429.066 us; speedup 1.0000x reference)
//
#include <hip/hip_runtime.h>

// InfluenceEncoder FUSED, 256-thread vehicle: B=4096, N=257, D=16, H=128.
// 1024 blocks x 256 thr (4 waves); block = 4 batches; wave = 1 FULL batch.
// Phase 1 (per wave, batch b = blockIdx*4+wv): 8 m-tiles x 4 col-tiles of
//   mfma_f32_32x32x16_f16, depth-2 A pipeline. Weights from A-regs (x,y at
//   k=0,1; f6 at k=6) by lo lanes -> wave-private LDS slice (same-wave DS
//   ordering, barrier-free). relu-bias fold: relu(e+b)=max(e,-b)+b.
//   Epilogue: xor32 combine, wsum butterfly, ragg[wv] = relu(pacc*inv+bfc)
//   as f16 in LDS [4][136].
// Phase 2 (ONE barrier): wave wv -> cols [32wv,32wv+32): 2 ct x 4 kk of
//   mfma_f32_16x16x32_f16 vs Wagg^T, A rows = ragg[lr&3] (4 real batches,
//   duplicated); bias via C-operand; store rows 0-3 from lq==0 lanes.
// Single launch, no workspace round-trip.
// REGISTER RULES (R5/R7/R9): min=max waves_per_eu ONLY, and ONLY with
// 256-thread blocks (512-thr blocks ignored the pin -> 64 VGPR + spill).

typedef _Float16 half_t;
typedef half_t f16x8 __attribute__((ext_vector_type(8)));
typedef float f32x4 __attribute__((ext_vector_type(4)));
typedef float f32x16 __attribute__((ext_vector_type(16)));

__global__ __launch_bounds__(256)
__attribute__((amdgpu_waves_per_eu(4, 4)))
void fused_kernel(
    const float* __restrict__ x,     // [4096,257,16]
    const float* __restrict__ Wfc,   // [128,16]
    const float* __restrict__ bfc,   // [128]
    const float* __restrict__ Wagg,  // [128,128]
    const float* __restrict__ bagg,  // [128]
    float* __restrict__ out)         // [4096,128]
{
    const int t    = threadIdx.x;
    const int lane = t & 63;
    const int wv   = t >> 6;      // 0..3 = batch slot in block
    const int lm   = lane & 31;
    const int hi   = lane >> 5;

    __shared__ float  wls[4][32];     // per-wave weight slice (per m-tile)
    __shared__ half_t ragg[4][136];   // relu(agg) f16 per batch slot, +pad

    const int b = blockIdx.x * 4 + wv;
    const float* xb = x + (size_t)b * (257 * 16);
    const float2 ego = *(const float2*)xb;

    // ---- B-frags (Wfc) + folded -bias ----
    f16x8 bfr[4];
    float nb[4];
    #pragma unroll
    for (int ct = 0; ct < 4; ++ct) {
        const float* wp = Wfc + (size_t)(ct * 32 + lm) * 16 + hi * 8;
        const float4 w0 = *(const float4*)wp;
        const float4 w1 = *(const float4*)(wp + 4);
        bfr[ct] = (f16x8){(half_t)w0.x, (half_t)w0.y, (half_t)w0.z, (half_t)w0.w,
                          (half_t)w1.x, (half_t)w1.y, (half_t)w1.z, (half_t)w1.w};
        nb[ct] = -bfc[ct * 32 + lm];
    }

    // ---- phase 1: 8 m-tiles (256 agents), depth-2 pipeline ----
    float4 s0[2], s1[2];
    #pragma unroll
    for (int i = 0; i < 2; ++i) {
        const float* rp = xb + (size_t)(1 + i * 32 + lm) * 16 + hi * 8;
        s0[i] = *(const float4*)rp;
        s1[i] = *(const float4*)(rp + 4);
    }

    float wsum = 0.f;
    float pacc[4] = {0.f, 0.f, 0.f, 0.f};

    #pragma unroll
    for (int tm = 0; tm < 8; ++tm) {
        const int cur = tm & 1;
        const float4 a0 = s0[cur], a1 = s1[cur];
        if (tm < 6) {
            const float* rp = xb + (size_t)(1 + (tm + 2) * 32 + lm) * 16 + hi * 8;
            s0[cur] = *(const float4*)rp;
            s1[cur] = *(const float4*)(rp + 4);
        }
        if (hi == 0) {   // weights from in-flight regs (k=0,1 pos; k=6 flag)
            const float dx = a0.x - ego.x, dy = a0.y - ego.y;
            float w = 1.0f / (sqrtf(dx * dx + dy * dy) + 1.0f);
            if (a1.z == 1.0f) w *= 5.0f;
            wls[wv][lm] = w;
            wsum += w;
        }
        const f16x8 afr = (f16x8){(half_t)a0.x, (half_t)a0.y, (half_t)a0.z, (half_t)a0.w,
                                  (half_t)a1.x, (half_t)a1.y, (half_t)a1.z, (half_t)a1.w};
        float4 w4[4];
        #pragma unroll
        for (int g = 0; g < 4; ++g)
            w4[g] = *(const float4*)(&wls[wv][g * 8 + hi * 4]);
        #pragma unroll
        for (int ct = 0; ct < 4; ++ct) {
            const f32x16 zc = {};
            const f32x16 d = __builtin_amdgcn_mfma_f32_32x32x16_f16(afr, bfr[ct], zc, 0, 0, 0);
            // D: col=lane&31, row=(r&3)+8*(r>>2)+4*hi
            #pragma unroll
            for (int r = 0; r < 16; ++r)
                pacc[ct] = fmaf(w4[r >> 2][r & 3], fmaxf(d[r], nb[ct]), pacc[ct]);
        }
    }

    // ---- phase-1 epilogue: combine, normalize, relu, to LDS ----
    #pragma unroll
    for (int ct = 0; ct < 4; ++ct) pacc[ct] += __shfl_xor(pacc[ct], 32);
    #pragma unroll
    for (int off = 32; off > 0; off >>= 1) wsum += __shfl_xor(wsum, off);
    const float inv = 1.0f / (wsum + 1e-10f);
    if (hi == 0) {
        #pragma unroll
        for (int ct = 0; ct < 4; ++ct) {
            const float e = fmaxf(fmaf(pacc[ct], inv, -nb[ct]), 0.f);
            ragg[wv][ct * 32 + lm] = (half_t)e;
        }
    }
    __syncthreads();

    // ---- phase 2: out(4x128) = ragg @ Wagg^T + bagg ----
    const int lr = lane & 15;
    const int lq = lane >> 4;

    #pragma unroll
    for (int ci = 0; ci < 2; ++ci) {
        const int col = wv * 32 + ci * 16 + lr;
        const float bb = bagg[col];
        f32x4 acc = (f32x4){bb, bb, bb, bb};
        const float* wrow = Wagg + (size_t)col * 128;
        #pragma unroll
        for (int kk = 0; kk < 4; ++kk) {
            const int k0 = kk * 32 + lq * 8;
            const f16x8 a = *(const f16x8*)(&ragg[lr & 3][k0]);  // rows repeat mod 4
            const float4 wg0 = *(const float4*)(wrow + k0);
            const float4 wg1 = *(const float4*)(wrow + k0 + 4);
            const f16x8 bf = (f16x8){(half_t)wg0.x, (half_t)wg0.y, (half_t)wg0.z, (half_t)wg0.w,
                                     (half_t)wg1.x, (half_t)wg1.y, (half_t)wg1.z, (half_t)wg1.w};
            acc = __builtin_amdgcn_mfma_f32_16x16x32_f16(a, bf, acc, 0, 0, 0);
        }
        // D: col=lane&15, row=lq*4+jj; rows 4-15 duplicate batches 0-3
        if (lq == 0) {
            #pragma unroll
            for (int jj = 0; jj < 4; ++jj)
                out[(size_t)(blockIdx.x * 4 + jj) * 128 + col] = acc[jj];
        }
    }
}

extern "C" void kernel_launch(void* const* d_in, const int* in_sizes, int n_in,
                              void* d_out, int out_size, void* d_ws, size_t ws_size,
                              hipStream_t stream) {
    const float* x    = (const float*)d_in[0];
    const float* Wfc  = (const float*)d_in[1];
    const float* bfc  = (const float*)d_in[2];
    const float* Wagg = (const float*)d_in[3];
    const float* bagg = (const float*)d_in[4];
    float* out = (float*)d_out;

    fused_kernel<<<dim3(1024), dim3(256), 0, stream>>>(x, Wfc, bfc, Wagg, bagg, out);
}

// Round 12
// 30.868 us; speedup vs baseline: 13.9002x; 13.9002x over previous
//
#include <hip/hip_runtime.h>

// InfluenceEncoder FUSED (graft onto R6's proven-codegen body).
// B=4096, N=257, D=16, H=128. 2048 blocks x 256 thr (4 waves) = 2 batches.
// Wave wv: batch b0+(wv>>1), half hf=wv&1 (128 agents) — IDENTICAL body to
// R6's agg_kernel (all-up-front A loads, no runtime-indexed reg arrays:
// every spilling build R5/R10/R11 had the depth-2 s0[tm&1] pattern; every
// clean build R4/R6/R8 had this one).
// Phase 1 epilogue -> LDS partials; barrier; 256 thr finish renorm+bias+relu
// -> ragg[2][136] f16; barrier; phase 2: wave wv does cols [32wv,32wv+32):
// 2 x 4 mfma_f32_16x16x32_f16 vs Wagg^T (A rows = 2 batches duplicated),
// bias in C-operand, store rows 0-1. No workspace, single launch.

typedef _Float16 half_t;
typedef half_t f16x8 __attribute__((ext_vector_type(8)));
typedef float f32x4 __attribute__((ext_vector_type(4)));
typedef float f32x16 __attribute__((ext_vector_type(16)));

__global__ __launch_bounds__(256)
__attribute__((amdgpu_waves_per_eu(4, 4)))
void fused_kernel(
    const float* __restrict__ x,     // [4096,257,16]
    const float* __restrict__ Wfc,   // [128,16]
    const float* __restrict__ bfc,   // [128]
    const float* __restrict__ Wagg,  // [128,128]
    const float* __restrict__ bagg,  // [128]
    float* __restrict__ out)         // [4096,128]
{
    const int t    = threadIdx.x;
    const int lane = t & 63;
    const int wv   = t >> 6;
    const int b0   = blockIdx.x * 2;
    const int b    = b0 + (wv >> 1);
    const int hf   = wv & 1;
    const int lm   = lane & 31;   // row-in-tile (A) / col-in-tile (B,D)
    const int hi   = lane >> 5;   // k-octet

    __shared__ float  wls[4][128];    // per-wave unnormalized weights
    __shared__ float  paggs[4][128];  // per-wave (half-batch) partials
    __shared__ float  wsums[4];
    __shared__ half_t ragg[2][136];   // relu(agg) f16 per batch, +pad

    const float* xb = x + (size_t)b * (257 * 16);
    const int row0 = 1 + hf * 128;

    // ---- A-tile loads (all up-front, R6 body) ----
    float4 a0[4], a1[4];
    #pragma unroll
    for (int tm = 0; tm < 4; ++tm) {
        const float* rp = xb + (size_t)(row0 + tm * 32 + lm) * 16 + hi * 8;
        a0[tm] = *(const float4*)rp;
        a1[tm] = *(const float4*)(rp + 4);
    }

    // ---- B-frags: B[k=hi*8+j][col=ct*32+lm] = Wfc[ct*32+lm][hi*8+j] ----
    f16x8 bfr[4];
    #pragma unroll
    for (int ct = 0; ct < 4; ++ct) {
        const float* wp = Wfc + (size_t)(ct * 32 + lm) * 16 + hi * 8;
        const float4 w0 = *(const float4*)wp;
        const float4 w1 = *(const float4*)(wp + 4);
        bfr[ct] = (f16x8){(half_t)w0.x, (half_t)w0.y, (half_t)w0.z, (half_t)w0.w,
                          (half_t)w1.x, (half_t)w1.y, (half_t)w1.z, (half_t)w1.w};
    }

    float nb[4];   // -bias for relu-fold
    #pragma unroll
    for (int ct = 0; ct < 4; ++ct) nb[ct] = -bfc[ct * 32 + lm];

    const float2 ego = *(const float2*)xb;

    // ---- weights from A regs (lo lanes hold k=0..7: x,y at 0,1; f6 at 6) ----
    float wsum = 0.f;
    if (hi == 0) {
        #pragma unroll
        for (int tm = 0; tm < 4; ++tm) {
            const float dx = a0[tm].x - ego.x;
            const float dy = a0[tm].y - ego.y;
            float w = 1.0f / (sqrtf(dx * dx + dy * dy) + 1.0f);
            if (a1[tm].z == 1.0f) w *= 5.0f;   // k=6
            wls[wv][tm * 32 + lm] = w;
            wsum += w;
        }
    }
    #pragma unroll
    for (int off = 32; off > 0; off >>= 1) wsum += __shfl_xor(wsum, off);

    // ---- cvt A to f16 frags ----
    f16x8 afr[4];
    #pragma unroll
    for (int tm = 0; tm < 4; ++tm)
        afr[tm] = (f16x8){(half_t)a0[tm].x, (half_t)a0[tm].y, (half_t)a0[tm].z, (half_t)a0[tm].w,
                          (half_t)a1[tm].x, (half_t)a1[tm].y, (half_t)a1[tm].z, (half_t)a1[tm].w};

    // ---- MFMA + fold-relu weighted row-agg ----
    // D layout: col=lane&31, row=(r&3)+8*(r>>2)+4*hi
    float pacc[4] = {0.f, 0.f, 0.f, 0.f};
    #pragma unroll
    for (int tm = 0; tm < 4; ++tm) {
        float4 w4[4];
        #pragma unroll
        for (int g = 0; g < 4; ++g)
            w4[g] = *(const float4*)(&wls[wv][tm * 32 + g * 8 + hi * 4]);
        #pragma unroll
        for (int ct = 0; ct < 4; ++ct) {
            f32x16 zc = {};
            const f32x16 d = __builtin_amdgcn_mfma_f32_32x32x16_f16(afr[tm], bfr[ct], zc, 0, 0, 0);
            #pragma unroll
            for (int r = 0; r < 16; ++r)
                pacc[ct] = fmaf(w4[r >> 2][r & 3], fmaxf(d[r], nb[ct]), pacc[ct]);
        }
    }

    // ---- epilogue: combine k-octets, partials to LDS ----
    #pragma unroll
    for (int ct = 0; ct < 4; ++ct) pacc[ct] += __shfl_xor(pacc[ct], 32);
    if (hi == 0) {
        #pragma unroll
        for (int ct = 0; ct < 4; ++ct) paggs[wv][ct * 32 + lm] = pacc[ct];
        if (lane == 0) wsums[wv] = wsum;
    }
    __syncthreads();

    // ---- finish: renorm + bias + relu -> ragg f16 (256 thr = 2x128) ----
    {
        const int bb = t >> 7;          // batch slot 0/1
        const int c  = t & 127;
        const float p = paggs[bb * 2][c] + paggs[bb * 2 + 1][c];
        const float inv = 1.0f / (wsums[bb * 2] + wsums[bb * 2 + 1] + 1e-10f);
        ragg[bb][c] = (half_t)fmaxf(fmaf(p, inv, bfc[c]), 0.f);
    }
    __syncthreads();

    // ---- phase 2: out(2x128) = ragg @ Wagg^T + bagg ----
    const int lr = lane & 15;
    const int lq = lane >> 4;

    #pragma unroll
    for (int ci = 0; ci < 2; ++ci) {
        const int col = wv * 32 + ci * 16 + lr;
        const float bb2 = bagg[col];
        f32x4 acc = (f32x4){bb2, bb2, bb2, bb2};
        const float* wrow = Wagg + (size_t)col * 128;
        #pragma unroll
        for (int kk = 0; kk < 4; ++kk) {
            const int k0 = kk * 32 + lq * 8;
            const f16x8 a = *(const f16x8*)(&ragg[lr & 1][k0]);  // rows repeat mod 2
            const float4 wg0 = *(const float4*)(wrow + k0);
            const float4 wg1 = *(const float4*)(wrow + k0 + 4);
            const f16x8 bf = (f16x8){(half_t)wg0.x, (half_t)wg0.y, (half_t)wg0.z, (half_t)wg0.w,
                                     (half_t)wg1.x, (half_t)wg1.y, (half_t)wg1.z, (half_t)wg1.w};
            acc = __builtin_amdgcn_mfma_f32_16x16x32_f16(a, bf, acc, 0, 0, 0);
        }
        // D: col=lane&15, row=lq*4+jj; rows 0,1 are the real batches
        if (lq == 0) {
            #pragma unroll
            for (int jj = 0; jj < 2; ++jj)
                out[(size_t)(b0 + jj) * 128 + col] = acc[jj];
        }
    }
}

extern "C" void kernel_launch(void* const* d_in, const int* in_sizes, int n_in,
                              void* d_out, int out_size, void* d_ws, size_t ws_size,
                              hipStream_t stream) {
    const float* x    = (const float*)d_in[0];
    const float* Wfc  = (const float*)d_in[1];
    const float* bfc  = (const float*)d_in[2];
    const float* Wagg = (const float*)d_in[3];
    const float* bagg = (const float*)d_in[4];
    float* out = (float*)d_out;

    fused_kernel<<<dim3(2048), dim3(256), 0, stream>>>(x, Wfc, bfc, Wagg, bagg, out);
}